// Round 1
// baseline (603.752 us; speedup 1.0000x reference)
//
#include <hip/hip_runtime.h>
#include <hip/hip_cooperative_groups.h>
#include <stdint.h>

namespace cg = cooperative_groups;

#define NA 9
#define NC 80
#define NTOT 589824        // 256*256*9
#define TOPK 1000
#define CONF 0.05f
#define NMS_T 0.6
#define CTR_CLAMP 32.0
#define IMGF 2048.0
#define SCALE_CLAMP 4.135166556742356   // log(1000/16)

// ---- workspace byte offsets ----
#define BITS_OFF   0u          // NTOT u32 f32-score bits, planar [a][hw]
#define LABELS_OFF 2359296u    // NTOT i32, planar
#define HIST_OFF   4718592u    // 16384 u32
#define CNT_OFF    4784128u    // u32
#define CUTB_OFF   4784132u    // u32
#define CAND_OFF   4784384u    // 4096 u64
#define BOXES_OFF  4817152u    // 4000 f32
#define LABS_OFF   4833152u    // 1000 i32
#define SUPB_OFF   4837376u    // 16*1024 u64 transposed

// ---- cephes f32 exp/log (matches the CPU reference's rounding; DO NOT TOUCH) ----
__device__ __forceinline__ float cexpf(float x) {
#pragma clang fp contract(off)
  float m = floorf(__builtin_fmaf(x, 1.44269504088896341f, 0.5f));
  float r = __builtin_fmaf(m, -0.693359375f, x);
  r = __builtin_fmaf(m, 2.12194440e-4f, r);
  float r2 = r * r;
  float y = 1.9875691500E-4f;
  y = __builtin_fmaf(y, r, 1.3981999507E-3f);
  y = __builtin_fmaf(y, r, 8.3334519073E-3f);
  y = __builtin_fmaf(y, r, 4.1665795894E-2f);
  y = __builtin_fmaf(y, r, 1.6666665459E-1f);
  y = __builtin_fmaf(y, r, 5.0000001201E-1f);
  y = __builtin_fmaf(y, r2, r) + 1.0f;
  return ldexpf(y, (int)m);
}

__device__ __forceinline__ float clogf_(float xin) {
#pragma clang fp contract(off)
  unsigned b = __float_as_uint(xin);
  int e = (int)(b >> 23) - 126;
  float m = __uint_as_float((b & 0x007FFFFFu) | 0x3F000000u);
  if (m < 0.707106781186547524f) { e -= 1; m = m + m; }
  float x = m - 1.0f;
  float z = x * x;
  float y = 7.0376836292E-2f;
  y = __builtin_fmaf(y, x, -1.1514610310E-1f);
  y = __builtin_fmaf(y, x, 1.1676998740E-1f);
  y = __builtin_fmaf(y, x, -1.2420140846E-1f);
  y = __builtin_fmaf(y, x, 1.4249322787E-1f);
  y = __builtin_fmaf(y, x, -1.6668057665E-1f);
  y = __builtin_fmaf(y, x, 2.0000714765E-1f);
  y = __builtin_fmaf(y, x, -2.4999993993E-1f);
  y = __builtin_fmaf(y, x, 3.3333331174E-1f);
  y = y * x * z;
  float ef = (float)e;
  y = __builtin_fmaf(ef, -2.12194440e-4f, y);
  y = __builtin_fmaf(-0.5f, z, y);
  float res = x + y;
  res = __builtin_fmaf(ef, 0.693359375f, res);
  return res;
}

// Scores (u32 bits, planar) + argmax labels (planar) + FUSED 16384-bin histogram
// (LDS-privatized, nonzero-bin global merge). UNCHANGED from verified version.
__global__ __launch_bounds__(256) void k_score(const float4* __restrict__ obj4,
                                               const float4* __restrict__ cls4,
                                               unsigned* __restrict__ bits_all,
                                               int* __restrict__ labels_all,
                                               unsigned* __restrict__ hist) {
#pragma clang fp contract(off)
  __shared__ unsigned lh[16384];
  int tid = threadIdx.x;
  for (int b = tid; b < 16384; b += 256) lh[b] = 0u;
  __syncthreads();
  int t = blockIdx.x * 256 + tid;            // [0, NTOT/4)
  int a = t >> 14;
  int rem = t & 16383;
  float4 ov = obj4[t];
  float ob[4] = {ov.x, ov.y, ov.z, ov.w};
  float best[4] = {-1e30f, -1e30f, -1e30f, -1e30f};
  int bc[4] = {0, 0, 0, 0};
  const float4* cp = cls4 + a * 80 * 16384 + rem;
#pragma unroll 8
  for (int c = 0; c < 80; c++) {
    float4 cv = cp[c * 16384];
    float cl[4] = {cv.x, cv.y, cv.z, cv.w};
#pragma unroll
    for (int k = 0; k < 4; k++) {
      if (cl[k] > best[k]) { best[k] = cl[k]; bc[k] = c; }  // strict >: first max
    }
  }
  unsigned bv[4];
#pragma unroll
  for (int k = 0; k < 4; k++) {
    float c = best[k], o = ob[k];
    float ec = cexpf(c);
    float eo = cexpf(o);
    float L = clogf_((1.0f + ec) + eo);
    float nrm = (c + o) - L;
    float p = 1.0f / (1.0f + cexpf(-nrm));
    bv[k] = __float_as_uint(p);              // p in (0,1): order == bit order
    atomicAdd(&lh[bv[k] >> 16], 1u);
  }
  unsigned po = (unsigned)(a * 65536 + rem * 4);  // planar, contiguous
#pragma unroll
  for (int k = 0; k < 4; k++) { bits_all[po + k] = bv[k]; labels_all[po + k] = bc[k]; }
  __syncthreads();
  for (int b = tid; b < 16384; b += 256) {
    unsigned v = lh[b];
    if (v) atomicAdd(&hist[b], v);
  }
}

__device__ __forceinline__ unsigned long long shflxor64(unsigned long long v, int m) {
  unsigned lo = __shfl_xor((unsigned)v, m, 64);
  unsigned hi = __shfl_xor((unsigned)(v >> 32), m, 64);
  return ((unsigned long long)hi << 32) | lo;
}

// Fused tail: cutoff(block0) -> compact -> rank/decode -> sup matrix -> greedy NMS.
// One cooperative launch, 4 grid syncs, replaces 5 separate dispatches.
// 512 blocks x 256 threads; 20KB LDS => 8 blocks/CU by LDS, need only 2/CU.
__global__ __launch_bounds__(256) void k_tail(const unsigned* __restrict__ hist,
                                              const unsigned* __restrict__ bits_all,
                                              const int* __restrict__ labels_all,
                                              const float* __restrict__ reg_pred,
                                              const float* __restrict__ anchors,
                                              unsigned* __restrict__ cutB,
                                              unsigned* __restrict__ cand_cnt,
                                              unsigned long long* __restrict__ cand,
                                              float* __restrict__ out,
                                              float* __restrict__ boxes_s,
                                              int* __restrict__ labels_s,
                                              unsigned long long* __restrict__ supB) {
  cg::grid_group grid = cg::this_grid();
  int tid = threadIdx.x;
  int bid = blockIdx.x;

  __shared__ __align__(16) char smem[20032];
  unsigned* s_cut = (unsigned*)smem;                       // 256 u32 (cutoff scan)
  unsigned long long* s_key = (unsigned long long*)smem;   // 256 u64 (rank tiles)
  float* s_bx = (float*)smem;                              // 4000 f32 (sup boxes)
  int* s_lb = (int*)(smem + 16000);                        // 1000 i32 (sup labels)
  __shared__ int sC;
  __shared__ unsigned sAbove;

  // ---- Phase A: cutoff bin (block 0; 256 threads over 16384 bins, 64/thread) ----
  if (bid == 0) {
    unsigned base = (unsigned)tid * 64u;
    unsigned s = 0;
    for (int b = 0; b < 64; b++) s += hist[base + b];
    unsigned v = s;
    s_cut[tid] = v;
    __syncthreads();
    for (int off = 1; off < 256; off <<= 1) {
      unsigned add = (tid + off < 256) ? s_cut[tid + off] : 0u;
      __syncthreads();
      v += add;
      s_cut[tid] = v;
      __syncthreads();
    }
    unsigned nxt = (tid < 255) ? s_cut[tid + 1] : 0u;
    if (v >= TOPK && nxt < TOPK) { sC = tid; sAbove = nxt; }
    __syncthreads();
    int C = sC;
    unsigned above = sAbove;
    if (tid < 64) {
      unsigned h = hist[(unsigned)C * 64u + (unsigned)tid];
      unsigned acc = h;
      // wave suffix-sum over 64 bins (high bin index = high score half)
      for (int off = 1; off < 64; off <<= 1) {
        unsigned o = __shfl_down(acc, off, 64);
        if (tid + off < 64) acc += o;
      }
      acc += above;
      if (acc >= TOPK && (tid == 63 || (acc - h) < TOPK))
        *cutB = (unsigned)(C * 64 + tid);
    }
  }
  grid.sync();

  // ---- Phase B: compact entries with bin >= cutB into u64 keys ----
  {
    unsigned cB = *cutB;
    for (unsigned t = (unsigned)bid * 256u + (unsigned)tid; t < (unsigned)NTOT;
         t += 131072u) {
      unsigned bits = bits_all[t];
      bool win = (bits >> 16) >= cB;
      unsigned long long m = __ballot(win);
      if (m != 0ull) {
        int lane = tid & 63;
        int leader = __ffsll((long long)m) - 1;
        unsigned base2 = 0;
        if (lane == leader) base2 = atomicAdd(cand_cnt, (unsigned)__popcll(m));
        base2 = __shfl(base2, leader, 64);
        if (win) {
          unsigned a = t >> 16;
          unsigned hw = t & 65535u;
          unsigned j = hw * 9u + a;
          unsigned pos = base2 + (unsigned)__popcll(m & ((1ull << lane) - 1ull));
          if (pos < 4096u)
            cand[pos] = ((unsigned long long)bits << 20) |
                        (unsigned long long)(0xFFFFFu - j);
        }
      }
    }
  }
  grid.sync();

  // ---- Phase C: rank-based top-1000 + box decode (blocks 0..15) ----
  if (bid < 16) {
    int c = bid * 256 + tid;
    unsigned M = *cand_cnt;
    if (M > 4096u) M = 4096u;
    unsigned long long mykey = (c < (int)M) ? cand[c] : 0ull;
    unsigned rank = 0;
    int ntile = (int)((M + 255u) >> 8);     // only real tiles (was fixed 16)
    for (int tile = 0; tile < ntile; tile++) {
      __syncthreads();
      int src = tile * 256 + tid;
      s_key[tid] = (src < (int)M) ? cand[src] : 0ull;
      __syncthreads();
#pragma unroll 8
      for (int q = 0; q < 256; q++) rank += (s_key[q] > mykey) ? 1u : 0u;
    }
    if (c < (int)M && rank < TOPK) {
      int r = (int)rank;
      unsigned j = 0xFFFFFu - (unsigned)(mykey & 0xFFFFFull);
      unsigned hw = j / 9u;
      unsigned a = j - hw * 9u;
      int lab = labels_all[a * 65536u + hw];
      unsigned base = a * 4u * 65536u + hw;
      double r0 = (double)reg_pred[base];
      double r1 = (double)reg_pred[base + 65536u];
      double r2 = (double)reg_pred[base + 131072u];
      double r3 = (double)reg_pred[base + 196608u];
      double ax = (double)anchors[j * 4u + 0], ay = (double)anchors[j * 4u + 1];
      double aw = (double)anchors[j * 4u + 2], ah = (double)anchors[j * 4u + 3];
      double ox = fmin(fmax(r0 * aw, -CTR_CLAMP), CTR_CLAMP);
      double oy = fmin(fmax(r1 * ah, -CTR_CLAMP), CTR_CLAMP);
      double cx = ax + ox, cy = ay + oy;
      double ww = aw * exp(fmin(r2, SCALE_CLAMP));
      double hh = ah * exp(fmin(r3, SCALE_CLAMP));
      float x1 = (float)fmin(fmax((cx - 0.5 * ww) * (1.0 / IMGF), 0.0), 1.0);
      float y1 = (float)fmin(fmax((cy - 0.5 * hh) * (1.0 / IMGF), 0.0), 1.0);
      float x2 = (float)fmin(fmax((cx + 0.5 * ww) * (1.0 / IMGF), 0.0), 1.0);
      float y2 = (float)fmin(fmax((cy + 0.5 * hh) * (1.0 / IMGF), 0.0), 1.0);
      out[r] = __uint_as_float((unsigned)(mykey >> 20));
      out[1000 + r] = (float)lab;
      out[2000 + 4 * r + 0] = x1;
      out[2000 + 4 * r + 1] = y1;
      out[2000 + 4 * r + 2] = x2;
      out[2000 + 4 * r + 3] = y2;
      boxes_s[4 * r + 0] = x1;
      boxes_s[4 * r + 1] = y1;
      boxes_s[4 * r + 2] = x2;
      boxes_s[4 * r + 3] = y2;
      labels_s[r] = lab;
    }
  }
  grid.sync();

  // ---- Phase D: suppression bit-matrix (rows i = bid and bid+512) ----
  for (int t = tid; t < 4000; t += 256) s_bx[t] = boxes_s[t];
  for (int t = tid; t < 1000; t += 256) s_lb[t] = labels_s[t];
  __syncthreads();
  for (int half = 0; half < 2; half++) {
    int i = bid + half * 512;
    if (i < TOPK) {
      double ix1 = (double)s_bx[4 * i], iy1 = (double)s_bx[4 * i + 1];
      double ix2 = (double)s_bx[4 * i + 2], iy2 = (double)s_bx[4 * i + 3];
      double ia = (ix2 - ix1) * (iy2 - iy1);
      int il = s_lb[i];
      for (int rep = 0; rep < 4; rep++) {
        int j = rep * 256 + tid;
        bool s = false;
        if (j < TOPK && j > i && s_lb[j] == il) {
          double jx1 = (double)s_bx[4 * j], jy1 = (double)s_bx[4 * j + 1];
          double jx2 = (double)s_bx[4 * j + 2], jy2 = (double)s_bx[4 * j + 3];
          double xx1 = fmax(ix1, jx1), yy1 = fmax(iy1, jy1);
          double xx2 = fmin(ix2, jx2), yy2 = fmin(iy2, jy2);
          double inter = fmax(1e-28, xx2 - xx1) * fmax(1e-28, yy2 - yy1);
          double ja = (jx2 - jx1) * (jy2 - jy1);
          double iou = inter / (ia + ja - inter + 1e-14);
          s = iou > NMS_T;
        }
        unsigned long long w = __ballot(s);
        if ((tid & 63) == 0) supB[(rep * 4 + (tid >> 6)) * 1024 + i] = w;
      }
    }
  }
  grid.sync();

  // ---- Phase E: greedy NMS (block 0, wave 0) ----
  if (bid == 0 && tid < 64) {
    int lane = tid;
    const float* scores = out;
    float* keep_out = out + 6000;
    unsigned long long inval[16];
#pragma unroll
    for (int m = 0; m < 16; m++) {
      int j = m * 64 + lane;
      bool bad = (j >= TOPK) || (scores[j] < CONF);
      inval[m] = __ballot(bad);
    }
    unsigned long long kept[16];
#pragma unroll
    for (int b = 0; b < 16; b++) {
      unsigned long long acc = 0ull;
#pragma unroll
      for (int m = 0; m < b; m++) {
        unsigned long long r = supB[b * 1024 + m * 64 + lane];
        if ((kept[m] >> lane) & 1ull) acc |= r;
      }
      if (b > 0) {
#pragma unroll
        for (int s = 1; s < 64; s <<= 1) acc |= shflxor64(acc, s);
      }
      unsigned alo = __builtin_amdgcn_readfirstlane((unsigned)acc);
      unsigned ahi = __builtin_amdgcn_readfirstlane((unsigned)(acc >> 32));
      unsigned long long cur = inval[b] | (((unsigned long long)ahi << 32) | alo);
      unsigned long long diag = supB[b * 1024 + b * 64 + lane];
      unsigned dlo = (unsigned)diag, dhi = (unsigned)(diag >> 32);
#pragma unroll 8
      for (int k = 0; k < 64; k++) {
        unsigned rlo = __builtin_amdgcn_readlane(dlo, k);
        unsigned rhi = __builtin_amdgcn_readlane(dhi, k);
        unsigned long long rk = ((unsigned long long)rhi << 32) | rlo;
        unsigned long long take = ((cur >> k) & 1ull) ? 0ull : rk;
        cur |= take;
      }
      kept[b] = ~cur;
    }
#pragma unroll
    for (int m = 0; m < 16; m++) {
      int j = m * 64 + lane;
      if (j < TOPK) keep_out[j] = ((kept[m] >> lane) & 1ull) ? 1.0f : 0.0f;
    }
  }
}

extern "C" void kernel_launch(void* const* d_in, const int* in_sizes, int n_in,
                              void* d_out, int out_size, void* d_ws, size_t ws_size,
                              hipStream_t stream) {
  const float* obj = (const float*)d_in[0];
  const float* cls = (const float*)d_in[1];
  const float* reg = (const float*)d_in[2];
  const float* anc = (const float*)d_in[3];
  float* out = (float*)d_out;
  char* ws = (char*)d_ws;

  unsigned* bits_all = (unsigned*)(ws + BITS_OFF);
  int* labels_all = (int*)(ws + LABELS_OFF);
  unsigned* hist = (unsigned*)(ws + HIST_OFF);
  unsigned* cand_cnt = (unsigned*)(ws + CNT_OFF);
  unsigned* cutB = (unsigned*)(ws + CUTB_OFF);
  unsigned long long* cand = (unsigned long long*)(ws + CAND_OFF);
  float* boxes_s = (float*)(ws + BOXES_OFF);
  int* labels_s = (int*)(ws + LABS_OFF);
  unsigned long long* supB = (unsigned long long*)(ws + SUPB_OFF);

  hipMemsetAsync(ws + HIST_OFF, 0, 65536 + 512, stream);

  k_score<<<576, 256, 0, stream>>>((const float4*)obj, (const float4*)cls, bits_all,
                                   labels_all, hist);

  void* kargs[] = {(void*)&hist,    (void*)&bits_all, (void*)&labels_all,
                   (void*)&reg,     (void*)&anc,      (void*)&cutB,
                   (void*)&cand_cnt, (void*)&cand,    (void*)&out,
                   (void*)&boxes_s, (void*)&labels_s, (void*)&supB};
  hipLaunchCooperativeKernel((const void*)k_tail, dim3(512), dim3(256), kargs, 0,
                             stream);
}

// Round 2
// 446.713 us; speedup vs baseline: 1.3515x; 1.3515x over previous
//
#include <hip/hip_runtime.h>
#include <stdint.h>

#define NA 9
#define NC 80
#define NTOT 589824        // 256*256*9
#define TOPK 1000
#define CONF 0.05f
#define NMS_T 0.6
#define CTR_CLAMP 32.0
#define IMGF 2048.0
#define SCALE_CLAMP 4.135166556742356   // log(1000/16)

// ---- workspace byte offsets ----
#define BITS_OFF   0u          // NTOT u32 f32-score bits, planar [a][hw]
#define LABELS_OFF 2359296u    // NTOT i32, planar
#define HIST_OFF   4718592u    // 16384 u32
#define CNT_OFF    4784128u    // u32 cand counter
#define BARS_OFF   4784160u    // 3 barriers x 8 split counters (u32)
#define CAND_OFF   4784384u    // 4096 u64
#define BOXES_OFF  4817152u    // 4000 f32
#define LABS_OFF   4833152u    // 1000 i32
#define SUPB_OFF   4837376u    // 16*1024 u64 transposed

#define NBLK 500

// ---- agent-scope (cross-XCD coherent, L2-bypassing) accessors ----
__device__ __forceinline__ void stg32(unsigned* p, unsigned v) {
  __hip_atomic_store(p, v, __ATOMIC_RELAXED, __HIP_MEMORY_SCOPE_AGENT);
}
__device__ __forceinline__ unsigned ldg32(const unsigned* p) {
  return __hip_atomic_load((unsigned*)p, __ATOMIC_RELAXED, __HIP_MEMORY_SCOPE_AGENT);
}
__device__ __forceinline__ void stg64(unsigned long long* p, unsigned long long v) {
  __hip_atomic_store(p, v, __ATOMIC_RELAXED, __HIP_MEMORY_SCOPE_AGENT);
}
__device__ __forceinline__ unsigned long long ldg64(const unsigned long long* p) {
  return __hip_atomic_load((unsigned long long*)p, __ATOMIC_RELAXED,
                           __HIP_MEMORY_SCOPE_AGENT);
}

// ---- lightweight device barrier: no cache maintenance; relies on all
// cross-barrier data being published via stg*/ldg* (coherence point).
// Release ordering: caller's __syncthreads() drains vmcnt in every wave
// of the block BEFORE tid0 increments the counter.
__device__ __forceinline__ void bar_arrive(unsigned* b8, int bid) {
  __hip_atomic_fetch_add(&b8[bid & 7], 1u, __ATOMIC_RELAXED,
                         __HIP_MEMORY_SCOPE_AGENT);
}
__device__ __forceinline__ void bar_wait(unsigned* b8, unsigned target) {
  if (threadIdx.x == 0) {
    for (;;) {
      unsigned s = 0;
#pragma unroll
      for (int i = 0; i < 8; i++)
        s += __hip_atomic_load(&b8[i], __ATOMIC_RELAXED, __HIP_MEMORY_SCOPE_AGENT);
      if (s >= target) break;
      __builtin_amdgcn_s_sleep(2);
    }
  }
  __syncthreads();
  asm volatile("" ::: "memory");
}

// ---- cephes f32 exp/log (matches the CPU reference's rounding; DO NOT TOUCH) ----
__device__ __forceinline__ float cexpf(float x) {
#pragma clang fp contract(off)
  float m = floorf(__builtin_fmaf(x, 1.44269504088896341f, 0.5f));
  float r = __builtin_fmaf(m, -0.693359375f, x);
  r = __builtin_fmaf(m, 2.12194440e-4f, r);
  float r2 = r * r;
  float y = 1.9875691500E-4f;
  y = __builtin_fmaf(y, r, 1.3981999507E-3f);
  y = __builtin_fmaf(y, r, 8.3334519073E-3f);
  y = __builtin_fmaf(y, r, 4.1665795894E-2f);
  y = __builtin_fmaf(y, r, 1.6666665459E-1f);
  y = __builtin_fmaf(y, r, 5.0000001201E-1f);
  y = __builtin_fmaf(y, r2, r) + 1.0f;
  return ldexpf(y, (int)m);
}

__device__ __forceinline__ float clogf_(float xin) {
#pragma clang fp contract(off)
  unsigned b = __float_as_uint(xin);
  int e = (int)(b >> 23) - 126;
  float m = __uint_as_float((b & 0x007FFFFFu) | 0x3F000000u);
  if (m < 0.707106781186547524f) { e -= 1; m = m + m; }
  float x = m - 1.0f;
  float z = x * x;
  float y = 7.0376836292E-2f;
  y = __builtin_fmaf(y, x, -1.1514610310E-1f);
  y = __builtin_fmaf(y, x, 1.1676998740E-1f);
  y = __builtin_fmaf(y, x, -1.2420140846E-1f);
  y = __builtin_fmaf(y, x, 1.4249322787E-1f);
  y = __builtin_fmaf(y, x, -1.6668057665E-1f);
  y = __builtin_fmaf(y, x, 2.0000714765E-1f);
  y = __builtin_fmaf(y, x, -2.4999993993E-1f);
  y = __builtin_fmaf(y, x, 3.3333331174E-1f);
  y = y * x * z;
  float ef = (float)e;
  y = __builtin_fmaf(ef, -2.12194440e-4f, y);
  y = __builtin_fmaf(-0.5f, z, y);
  float res = x + y;
  res = __builtin_fmaf(ef, 0.693359375f, res);
  return res;
}

// Scores (u32 bits, planar) + argmax labels (planar) + FUSED 16384-bin histogram.
// UNCHANGED from harness-verified version.
__global__ __launch_bounds__(256) void k_score(const float4* __restrict__ obj4,
                                               const float4* __restrict__ cls4,
                                               unsigned* __restrict__ bits_all,
                                               int* __restrict__ labels_all,
                                               unsigned* __restrict__ hist) {
#pragma clang fp contract(off)
  __shared__ unsigned lh[16384];
  int tid = threadIdx.x;
  for (int b = tid; b < 16384; b += 256) lh[b] = 0u;
  __syncthreads();
  int t = blockIdx.x * 256 + tid;            // [0, NTOT/4)
  int a = t >> 14;
  int rem = t & 16383;
  float4 ov = obj4[t];
  float ob[4] = {ov.x, ov.y, ov.z, ov.w};
  float best[4] = {-1e30f, -1e30f, -1e30f, -1e30f};
  int bc[4] = {0, 0, 0, 0};
  const float4* cp = cls4 + a * 80 * 16384 + rem;
#pragma unroll 8
  for (int c = 0; c < 80; c++) {
    float4 cv = cp[c * 16384];
    float cl[4] = {cv.x, cv.y, cv.z, cv.w};
#pragma unroll
    for (int k = 0; k < 4; k++) {
      if (cl[k] > best[k]) { best[k] = cl[k]; bc[k] = c; }  // strict >: first max
    }
  }
  unsigned bv[4];
#pragma unroll
  for (int k = 0; k < 4; k++) {
    float c = best[k], o = ob[k];
    float ec = cexpf(c);
    float eo = cexpf(o);
    float L = clogf_((1.0f + ec) + eo);
    float nrm = (c + o) - L;
    float p = 1.0f / (1.0f + cexpf(-nrm));
    bv[k] = __float_as_uint(p);              // p in (0,1): order == bit order
    atomicAdd(&lh[bv[k] >> 16], 1u);
  }
  unsigned po = (unsigned)(a * 65536 + rem * 4);  // planar, contiguous
#pragma unroll
  for (int k = 0; k < 4; k++) { bits_all[po + k] = bv[k]; labels_all[po + k] = bc[k]; }
  __syncthreads();
  for (int b = tid; b < 16384; b += 256) {
    unsigned v = lh[b];
    if (v) atomicAdd(&hist[b], v);
  }
}

__device__ __forceinline__ unsigned long long shflxor64(unsigned long long v, int m) {
  unsigned lo = __shfl_xor((unsigned)v, m, 64);
  unsigned hi = __shfl_xor((unsigned)(v >> 32), m, 64);
  return ((unsigned long long)hi << 32) | lo;
}

// Fused tail v2: redundant per-block cutoff -> compact -> rank -> sup -> nms.
// Cooperative launch used ONLY for the co-residency guarantee; synchronization
// is custom counters + sc0sc1 publish/subscribe (no cg::grid.sync, no L2 flush).
__global__ __launch_bounds__(256) void k_tail2(const unsigned* __restrict__ hist,
                                               const unsigned* __restrict__ bits_all,
                                               const int* __restrict__ labels_all,
                                               const float* __restrict__ reg_pred,
                                               const float* __restrict__ anchors,
                                               unsigned* __restrict__ cand_cnt,
                                               unsigned* __restrict__ bars,
                                               unsigned long long* __restrict__ cand,
                                               float* __restrict__ out,
                                               float* __restrict__ boxes_s,
                                               int* __restrict__ labels_s,
                                               unsigned long long* __restrict__ supB) {
  int tid = threadIdx.x;
  int bid = blockIdx.x;

  __shared__ __align__(16) char smem[20480];
  unsigned* s_cut = (unsigned*)smem;                       // 1KB (cutoff scan)
  unsigned long long* s_key = (unsigned long long*)smem;   // 2KB (rank tiles)
  float* s_bx = (float*)smem;                              // 16KB (sup boxes)
  int* s_lb = (int*)(smem + 16000);                        // 4KB (sup labels)
  __shared__ int sC;
  __shared__ unsigned sAbove;
  __shared__ unsigned s_cutB;

  // ---- Phase A: cutoff bin, computed redundantly by EVERY block (determin-
  // istic from hist; removes one device barrier). hist from prior dispatch ->
  // plain cached loads are coherent. ----
  {
    unsigned base = (unsigned)tid * 64u;
    unsigned s = 0;
#pragma unroll 8
    for (int b = 0; b < 64; b++) s += hist[base + b];
    unsigned v = s;
    s_cut[tid] = v;
    __syncthreads();
    for (int off = 1; off < 256; off <<= 1) {
      unsigned add = (tid + off < 256) ? s_cut[tid + off] : 0u;
      __syncthreads();
      v += add;
      s_cut[tid] = v;
      __syncthreads();
    }
    unsigned nxt = (tid < 255) ? s_cut[tid + 1] : 0u;
    if (v >= TOPK && nxt < TOPK) { sC = tid; sAbove = nxt; }
    __syncthreads();
    int C = sC;
    unsigned above = sAbove;
    if (tid < 64) {
      unsigned h = hist[(unsigned)C * 64u + (unsigned)tid];
      unsigned acc = h;
      for (int off = 1; off < 64; off <<= 1) {
        unsigned o = __shfl_down(acc, off, 64);
        if (tid + off < 64) acc += o;
      }
      acc += above;
      if (acc >= TOPK && (tid == 63 || (acc - h) < TOPK))
        s_cutB = (unsigned)(C * 64 + tid);
    }
    __syncthreads();
  }
  unsigned cB = s_cutB;

  // ---- Phase B: compact entries with bin >= cutB into u64 keys (publish) ----
  for (unsigned t = (unsigned)bid * 256u + (unsigned)tid; t < (unsigned)NTOT;
       t += (unsigned)(NBLK * 256)) {
    unsigned bits = bits_all[t];
    bool win = (bits >> 16) >= cB;
    unsigned long long m = __ballot(win);
    if (m != 0ull) {
      int lane = tid & 63;
      int leader = __ffsll((long long)m) - 1;
      unsigned base2 = 0;
      if (lane == leader) base2 = atomicAdd(cand_cnt, (unsigned)__popcll(m));
      base2 = __shfl(base2, leader, 64);
      if (win) {
        unsigned a = t >> 16;
        unsigned hw = t & 65535u;
        unsigned j = hw * 9u + a;
        unsigned pos = base2 + (unsigned)__popcll(m & ((1ull << lane) - 1ull));
        if (pos < 4096u)
          stg64(&cand[pos], ((unsigned long long)bits << 20) |
                                (unsigned long long)(0xFFFFFu - j));
      }
    }
  }
  __syncthreads();                       // drains vmcnt: publishes cand
  if (tid == 0) bar_arrive(bars + 0, bid);
  bar_wait(bars + 0, NBLK);

  // ---- Phase C: rank-based top-1000 + box decode (blocks 0..15) ----
  if (bid < 16) {
    int c = bid * 256 + tid;
    unsigned M = ldg32(cand_cnt);
    if (M > 4096u) M = 4096u;
    unsigned long long mykey = (c < (int)M) ? ldg64(&cand[c]) : 0ull;
    unsigned rank = 0;
    int ntile = (int)((M + 255u) >> 8);
    for (int tile = 0; tile < ntile; tile++) {
      __syncthreads();
      int src = tile * 256 + tid;
      s_key[tid] = (src < (int)M) ? ldg64(&cand[src]) : 0ull;
      __syncthreads();
#pragma unroll 8
      for (int q = 0; q < 256; q++) rank += (s_key[q] > mykey) ? 1u : 0u;
    }
    if (c < (int)M && rank < TOPK) {
      int r = (int)rank;
      unsigned j = 0xFFFFFu - (unsigned)(mykey & 0xFFFFFull);
      unsigned hw = j / 9u;
      unsigned a = j - hw * 9u;
      int lab = labels_all[a * 65536u + hw];
      unsigned base = a * 4u * 65536u + hw;
      double r0 = (double)reg_pred[base];
      double r1 = (double)reg_pred[base + 65536u];
      double r2 = (double)reg_pred[base + 131072u];
      double r3 = (double)reg_pred[base + 196608u];
      double ax = (double)anchors[j * 4u + 0], ay = (double)anchors[j * 4u + 1];
      double aw = (double)anchors[j * 4u + 2], ah = (double)anchors[j * 4u + 3];
      double ox = fmin(fmax(r0 * aw, -CTR_CLAMP), CTR_CLAMP);
      double oy = fmin(fmax(r1 * ah, -CTR_CLAMP), CTR_CLAMP);
      double cx = ax + ox, cy = ay + oy;
      double ww = aw * exp(fmin(r2, SCALE_CLAMP));
      double hh = ah * exp(fmin(r3, SCALE_CLAMP));
      float x1 = (float)fmin(fmax((cx - 0.5 * ww) * (1.0 / IMGF), 0.0), 1.0);
      float y1 = (float)fmin(fmax((cy - 0.5 * hh) * (1.0 / IMGF), 0.0), 1.0);
      float x2 = (float)fmin(fmax((cx + 0.5 * ww) * (1.0 / IMGF), 0.0), 1.0);
      float y2 = (float)fmin(fmax((cy + 0.5 * hh) * (1.0 / IMGF), 0.0), 1.0);
      // final outputs read only by host: plain stores are fine
      out[1000 + r] = (float)lab;
      out[2000 + 4 * r + 0] = x1;
      out[2000 + 4 * r + 1] = y1;
      out[2000 + 4 * r + 2] = x2;
      out[2000 + 4 * r + 3] = y2;
      // values read by later phases: agent-scope publish
      stg32((unsigned*)&out[r], (unsigned)(mykey >> 20));
      stg32((unsigned*)&boxes_s[4 * r + 0], __float_as_uint(x1));
      stg32((unsigned*)&boxes_s[4 * r + 1], __float_as_uint(y1));
      stg32((unsigned*)&boxes_s[4 * r + 2], __float_as_uint(x2));
      stg32((unsigned*)&boxes_s[4 * r + 3], __float_as_uint(y2));
      stg32((unsigned*)&labels_s[r], (unsigned)lab);
    }
  }
  __syncthreads();                       // drains vmcnt: publishes boxes/labels
  if (tid == 0 && bid < 16) bar_arrive(bars + 8, bid);
  bar_wait(bars + 8, 16);

  // ---- Phase D: suppression bit-matrix (rows bid and bid+500) ----
  for (int t = tid; t < 4000; t += 256)
    s_bx[t] = __uint_as_float(ldg32((const unsigned*)&boxes_s[t]));
  for (int t = tid; t < 1000; t += 256)
    s_lb[t] = (int)ldg32((const unsigned*)&labels_s[t]);
  __syncthreads();
  for (int half = 0; half < 2; half++) {
    int i = bid + half * NBLK;
    double ix1 = (double)s_bx[4 * i], iy1 = (double)s_bx[4 * i + 1];
    double ix2 = (double)s_bx[4 * i + 2], iy2 = (double)s_bx[4 * i + 3];
    double ia = (ix2 - ix1) * (iy2 - iy1);
    int il = s_lb[i];
    for (int rep = 0; rep < 4; rep++) {
      int j = rep * 256 + tid;
      bool s = false;
      if (j < TOPK && j > i && s_lb[j] == il) {
        double jx1 = (double)s_bx[4 * j], jy1 = (double)s_bx[4 * j + 1];
        double jx2 = (double)s_bx[4 * j + 2], jy2 = (double)s_bx[4 * j + 3];
        double xx1 = fmax(ix1, jx1), yy1 = fmax(iy1, jy1);
        double xx2 = fmin(ix2, jx2), yy2 = fmin(iy2, jy2);
        double inter = fmax(1e-28, xx2 - xx1) * fmax(1e-28, yy2 - yy1);
        double ja = (jx2 - jx1) * (jy2 - jy1);
        double iou = inter / (ia + ja - inter + 1e-14);
        s = iou > NMS_T;
      }
      unsigned long long w = __ballot(s);
      if ((tid & 63) == 0)
        stg64(&supB[(rep * 4 + (tid >> 6)) * 1024 + i], w);
    }
  }
  __syncthreads();                       // drains vmcnt: publishes supB
  if (tid == 0) bar_arrive(bars + 16, bid);
  if (bid != 0) return;
  bar_wait(bars + 16, NBLK);

  // ---- Phase E: greedy NMS (block 0, wave 0) ----
  if (tid < 64) {
    int lane = tid;
    float* keep_out = out + 6000;
    unsigned long long inval[16];
#pragma unroll
    for (int m = 0; m < 16; m++) {
      int j = m * 64 + lane;
      bool bad = (j >= TOPK) ||
                 (__uint_as_float(ldg32((const unsigned*)&out[j])) < CONF);
      inval[m] = __ballot(bad);
    }
    unsigned long long kept[16];
#pragma unroll
    for (int b = 0; b < 16; b++) {
      unsigned long long acc = 0ull;
#pragma unroll
      for (int m = 0; m < b; m++) {
        unsigned long long r = ldg64(&supB[b * 1024 + m * 64 + lane]);
        if ((kept[m] >> lane) & 1ull) acc |= r;
      }
      if (b > 0) {
#pragma unroll
        for (int s = 1; s < 64; s <<= 1) acc |= shflxor64(acc, s);
      }
      unsigned alo = __builtin_amdgcn_readfirstlane((unsigned)acc);
      unsigned ahi = __builtin_amdgcn_readfirstlane((unsigned)(acc >> 32));
      unsigned long long cur = inval[b] | (((unsigned long long)ahi << 32) | alo);
      unsigned long long diag = ldg64(&supB[b * 1024 + b * 64 + lane]);
      unsigned dlo = (unsigned)diag, dhi = (unsigned)(diag >> 32);
#pragma unroll 8
      for (int k = 0; k < 64; k++) {
        unsigned rlo = __builtin_amdgcn_readlane(dlo, k);
        unsigned rhi = __builtin_amdgcn_readlane(dhi, k);
        unsigned long long rk = ((unsigned long long)rhi << 32) | rlo;
        unsigned long long take = ((cur >> k) & 1ull) ? 0ull : rk;
        cur |= take;
      }
      kept[b] = ~cur;
    }
#pragma unroll
    for (int m = 0; m < 16; m++) {
      int j = m * 64 + lane;
      if (j < TOPK) keep_out[j] = ((kept[m] >> lane) & 1ull) ? 1.0f : 0.0f;
    }
  }
}

extern "C" void kernel_launch(void* const* d_in, const int* in_sizes, int n_in,
                              void* d_out, int out_size, void* d_ws, size_t ws_size,
                              hipStream_t stream) {
  const float* obj = (const float*)d_in[0];
  const float* cls = (const float*)d_in[1];
  const float* reg = (const float*)d_in[2];
  const float* anc = (const float*)d_in[3];
  float* out = (float*)d_out;
  char* ws = (char*)d_ws;

  unsigned* bits_all = (unsigned*)(ws + BITS_OFF);
  int* labels_all = (int*)(ws + LABELS_OFF);
  unsigned* hist = (unsigned*)(ws + HIST_OFF);
  unsigned* cand_cnt = (unsigned*)(ws + CNT_OFF);
  unsigned* bars = (unsigned*)(ws + BARS_OFF);
  unsigned long long* cand = (unsigned long long*)(ws + CAND_OFF);
  float* boxes_s = (float*)(ws + BOXES_OFF);
  int* labels_s = (int*)(ws + LABS_OFF);
  unsigned long long* supB = (unsigned long long*)(ws + SUPB_OFF);

  // zeroes hist + cand_cnt + bars (all inside [HIST_OFF, HIST_OFF+66048))
  hipMemsetAsync(ws + HIST_OFF, 0, 65536 + 512, stream);

  k_score<<<576, 256, 0, stream>>>((const float4*)obj, (const float4*)cls, bits_all,
                                   labels_all, hist);

  void* kargs[] = {(void*)&hist,     (void*)&bits_all, (void*)&labels_all,
                   (void*)&reg,      (void*)&anc,      (void*)&cand_cnt,
                   (void*)&bars,     (void*)&cand,     (void*)&out,
                   (void*)&boxes_s,  (void*)&labels_s, (void*)&supB};
  hipLaunchCooperativeKernel((const void*)k_tail2, dim3(NBLK), dim3(256), kargs, 0,
                             stream);
}

// Round 4
// 403.377 us; speedup vs baseline: 1.4967x; 1.1074x over previous
//
#include <hip/hip_runtime.h>
#include <stdint.h>

#define NA 9
#define NC 80
#define NTOT 589824        // 256*256*9
#define TOPK 1000
#define CONF 0.05f
#define NMS_T 0.6
#define CTR_CLAMP 32.0
#define IMGF 2048.0
#define SCALE_CLAMP 4.135166556742356   // log(1000/16)

// ---- workspace byte offsets ----
// Sync words are padded to 256B lines: agent-scope ops serialize per LLC line,
// so every counter/flag gets its own line (round-2 lesson: shared line = ~30us/barrier).
#define BITS_OFF   0u          // NTOT u32 f32-score bits, planar [a][hw]
#define LABELS_OFF 2359296u    // NTOT i32, planar
#define HIST_OFF   4718592u    // 16384 u32 (64KB)
#define CNT_OFF    4784128u    // cand counter, own 256B line
#define BARC_OFF   4784384u    // 3 barriers x 8 counters, 256B stride (6144B)
#define FLAG_OFF   4790528u    // 3 barriers x 8 flag copies, 256B stride (6144B)
#define CAND_OFF   4796672u    // 4096 u64 (32KB)
#define BOXES_OFF  4829440u    // 4000 f32
#define LABS_OFF   4845440u    // 1000 i32
#define SUPB_OFF   4849664u    // 16*1024 u64 transposed (128KB)
#define ZERO_LEN   78080u      // HIST..FLAG end, one memset

#define NBLK 500
#define SPIN_CAP 200000        // ~12ms fail-fast: deadlock -> wrong answer, not hang

// ---- agent-scope (cross-XCD coherent, L2-bypassing) accessors ----
__device__ __forceinline__ void stg32(unsigned* p, unsigned v) {
  __hip_atomic_store(p, v, __ATOMIC_RELAXED, __HIP_MEMORY_SCOPE_AGENT);
}
__device__ __forceinline__ unsigned ldg32(const unsigned* p) {
  return __hip_atomic_load((unsigned*)p, __ATOMIC_RELAXED, __HIP_MEMORY_SCOPE_AGENT);
}
__device__ __forceinline__ void stg64(unsigned long long* p, unsigned long long v) {
  __hip_atomic_store(p, v, __ATOMIC_RELAXED, __HIP_MEMORY_SCOPE_AGENT);
}
__device__ __forceinline__ unsigned long long ldg64(const unsigned long long* p) {
  return __hip_atomic_load((unsigned long long*)p, __ATOMIC_RELAXED,
                           __HIP_MEMORY_SCOPE_AGENT);
}

__device__ __forceinline__ unsigned* lslot(unsigned* base, int idx) {
  return (unsigned*)((char*)base + (size_t)idx * 256u);
}

// Lightweight device barrier, no cache maintenance.
// Protocol: publish data (stg*) -> __syncthreads (vmcnt(0) = completion at LLC)
// -> tid0 arrival RMW -> block0 polls 8 counter lines, then writes 8 flag
// copies (separate lines) -> other blocks poll only their own flag copy.
__device__ __forceinline__ void barrier_sync(unsigned* cnts, unsigned* flags,
                                             int b, int bid, unsigned target,
                                             bool i_arrive) {
  __syncthreads();   // converge block + drain vmcnt: publishes prior stg* stores
  if (threadIdx.x == 0) {
    if (i_arrive)
      __hip_atomic_fetch_add(lslot(cnts, b * 8 + (bid & 7)), 1u, __ATOMIC_RELAXED,
                             __HIP_MEMORY_SCOPE_AGENT);
    if (bid == 0) {
      for (int it = 0; it < SPIN_CAP; it++) {
        unsigned s = 0;
#pragma unroll
        for (int i = 0; i < 8; i++)
          s += __hip_atomic_load(lslot(cnts, b * 8 + i), __ATOMIC_RELAXED,
                                 __HIP_MEMORY_SCOPE_AGENT);
        if (s >= target) break;
        __builtin_amdgcn_s_sleep(2);
      }
#pragma unroll
      for (int i = 0; i < 8; i++)
        __hip_atomic_store(lslot(flags, b * 8 + i), 1u, __ATOMIC_RELAXED,
                           __HIP_MEMORY_SCOPE_AGENT);
    } else {
      for (int it = 0; it < SPIN_CAP; it++) {
        if (__hip_atomic_load(lslot(flags, b * 8 + (bid & 7)), __ATOMIC_RELAXED,
                              __HIP_MEMORY_SCOPE_AGENT) != 0u)
          break;
        __builtin_amdgcn_s_sleep(2);
      }
    }
  }
  __syncthreads();
  asm volatile("" ::: "memory");
}

// ---- cephes f32 exp/log (matches the CPU reference's rounding; DO NOT TOUCH) ----
__device__ __forceinline__ float cexpf(float x) {
#pragma clang fp contract(off)
  float m = floorf(__builtin_fmaf(x, 1.44269504088896341f, 0.5f));
  float r = __builtin_fmaf(m, -0.693359375f, x);
  r = __builtin_fmaf(m, 2.12194440e-4f, r);
  float r2 = r * r;
  float y = 1.9875691500E-4f;
  y = __builtin_fmaf(y, r, 1.3981999507E-3f);
  y = __builtin_fmaf(y, r, 8.3334519073E-3f);
  y = __builtin_fmaf(y, r, 4.1665795894E-2f);
  y = __builtin_fmaf(y, r, 1.6666665459E-1f);
  y = __builtin_fmaf(y, r, 5.0000001201E-1f);
  y = __builtin_fmaf(y, r2, r) + 1.0f;
  return ldexpf(y, (int)m);
}

__device__ __forceinline__ float clogf_(float xin) {
#pragma clang fp contract(off)
  unsigned b = __float_as_uint(xin);
  int e = (int)(b >> 23) - 126;
  float m = __uint_as_float((b & 0x007FFFFFu) | 0x3F000000u);
  if (m < 0.707106781186547524f) { e -= 1; m = m + m; }
  float x = m - 1.0f;
  float z = x * x;
  float y = 7.0376836292E-2f;
  y = __builtin_fmaf(y, x, -1.1514610310E-1f);
  y = __builtin_fmaf(y, x, 1.1676998740E-1f);
  y = __builtin_fmaf(y, x, -1.2420140846E-1f);
  y = __builtin_fmaf(y, x, 1.4249322787E-1f);
  y = __builtin_fmaf(y, x, -1.6668057665E-1f);
  y = __builtin_fmaf(y, x, 2.0000714765E-1f);
  y = __builtin_fmaf(y, x, -2.4999993993E-1f);
  y = __builtin_fmaf(y, x, 3.3333331174E-1f);
  y = y * x * z;
  float ef = (float)e;
  y = __builtin_fmaf(ef, -2.12194440e-4f, y);
  y = __builtin_fmaf(-0.5f, z, y);
  float res = x + y;
  res = __builtin_fmaf(ef, 0.693359375f, res);
  return res;
}

// Scores + argmax labels + fused 16384-bin histogram. UNCHANGED (verified).
__global__ __launch_bounds__(256) void k_score(const float4* __restrict__ obj4,
                                               const float4* __restrict__ cls4,
                                               unsigned* __restrict__ bits_all,
                                               int* __restrict__ labels_all,
                                               unsigned* __restrict__ hist) {
#pragma clang fp contract(off)
  __shared__ unsigned lh[16384];
  int tid = threadIdx.x;
  for (int b = tid; b < 16384; b += 256) lh[b] = 0u;
  __syncthreads();
  int t = blockIdx.x * 256 + tid;            // [0, NTOT/4)
  int a = t >> 14;
  int rem = t & 16383;
  float4 ov = obj4[t];
  float ob[4] = {ov.x, ov.y, ov.z, ov.w};
  float best[4] = {-1e30f, -1e30f, -1e30f, -1e30f};
  int bc[4] = {0, 0, 0, 0};
  const float4* cp = cls4 + a * 80 * 16384 + rem;
#pragma unroll 8
  for (int c = 0; c < 80; c++) {
    float4 cv = cp[c * 16384];
    float cl[4] = {cv.x, cv.y, cv.z, cv.w};
#pragma unroll
    for (int k = 0; k < 4; k++) {
      if (cl[k] > best[k]) { best[k] = cl[k]; bc[k] = c; }  // strict >: first max
    }
  }
  unsigned bv[4];
#pragma unroll
  for (int k = 0; k < 4; k++) {
    float c = best[k], o = ob[k];
    float ec = cexpf(c);
    float eo = cexpf(o);
    float L = clogf_((1.0f + ec) + eo);
    float nrm = (c + o) - L;
    float p = 1.0f / (1.0f + cexpf(-nrm));
    bv[k] = __float_as_uint(p);              // p in (0,1): order == bit order
    atomicAdd(&lh[bv[k] >> 16], 1u);
  }
  unsigned po = (unsigned)(a * 65536 + rem * 4);  // planar, contiguous
#pragma unroll
  for (int k = 0; k < 4; k++) { bits_all[po + k] = bv[k]; labels_all[po + k] = bc[k]; }
  __syncthreads();
  for (int b = tid; b < 16384; b += 256) {
    unsigned v = lh[b];
    if (v) atomicAdd(&hist[b], v);
  }
}

__device__ __forceinline__ unsigned long long shflxor64(unsigned long long v, int m) {
  unsigned lo = __shfl_xor((unsigned)v, m, 64);
  unsigned hi = __shfl_xor((unsigned)(v >> 32), m, 64);
  return ((unsigned long long)hi << 32) | lo;
}

// Fused tail v3: redundant per-block cutoff -> compact -> rank -> sup -> nms.
// Sync = padded-line counters + single-releaser flag fanout (no L2 flush).
__global__ __launch_bounds__(256) void k_tail2(const unsigned* __restrict__ hist,
                                               const unsigned* __restrict__ bits_all,
                                               const int* __restrict__ labels_all,
                                               const float* __restrict__ reg_pred,
                                               const float* __restrict__ anchors,
                                               unsigned* __restrict__ cand_cnt,
                                               unsigned* __restrict__ barc,
                                               unsigned* __restrict__ flags,
                                               unsigned long long* __restrict__ cand,
                                               float* __restrict__ out,
                                               float* __restrict__ boxes_s,
                                               int* __restrict__ labels_s,
                                               unsigned long long* __restrict__ supB) {
  int tid = threadIdx.x;
  int bid = blockIdx.x;

  __shared__ __align__(16) char smem[20480];
  unsigned* s_cut = (unsigned*)smem;                       // 1KB (cutoff scan)
  unsigned long long* s_key = (unsigned long long*)smem;   // 2KB (rank tiles)
  float* s_bx = (float*)smem;                              // 16KB (sup boxes)
  int* s_lb = (int*)(smem + 16000);                        // 4KB (sup labels)
  __shared__ int sC;
  __shared__ unsigned sAbove;
  __shared__ unsigned s_cutB;

  // ---- Phase A: cutoff bin, redundantly per block (deterministic from hist;
  // hist written by prior dispatch -> plain cached loads coherent). ----
  {
    unsigned base = (unsigned)tid * 64u;
    unsigned s = 0;
#pragma unroll 8
    for (int b = 0; b < 64; b++) s += hist[base + b];
    unsigned v = s;
    s_cut[tid] = v;
    __syncthreads();
    for (int off = 1; off < 256; off <<= 1) {
      unsigned add = (tid + off < 256) ? s_cut[tid + off] : 0u;
      __syncthreads();
      v += add;
      s_cut[tid] = v;
      __syncthreads();
    }
    unsigned nxt = (tid < 255) ? s_cut[tid + 1] : 0u;
    if (v >= TOPK && nxt < TOPK) { sC = tid; sAbove = nxt; }
    __syncthreads();
    int C = sC;
    unsigned above = sAbove;
    if (tid < 64) {
      unsigned h = hist[(unsigned)C * 64u + (unsigned)tid];
      unsigned acc = h;
      for (int off = 1; off < 64; off <<= 1) {
        unsigned o = __shfl_down(acc, off, 64);
        if (tid + off < 64) acc += o;
      }
      acc += above;
      if (acc >= TOPK && (tid == 63 || (acc - h) < TOPK))
        s_cutB = (unsigned)(C * 64 + tid);
    }
    __syncthreads();
  }
  unsigned cB = s_cutB;

  // ---- Phase B: compact entries with bin >= cutB into u64 keys (publish) ----
  for (unsigned t = (unsigned)bid * 256u + (unsigned)tid; t < (unsigned)NTOT;
       t += (unsigned)(NBLK * 256)) {
    unsigned bits = bits_all[t];
    bool win = (bits >> 16) >= cB;
    unsigned long long m = __ballot(win);
    if (m != 0ull) {
      int lane = tid & 63;
      int leader = __ffsll((long long)m) - 1;
      unsigned base2 = 0;
      if (lane == leader) base2 = atomicAdd(cand_cnt, (unsigned)__popcll(m));
      base2 = __shfl(base2, leader, 64);
      if (win) {
        unsigned a = t >> 16;
        unsigned hw = t & 65535u;
        unsigned j = hw * 9u + a;
        unsigned pos = base2 + (unsigned)__popcll(m & ((1ull << lane) - 1ull));
        if (pos < 4096u)
          stg64(&cand[pos], ((unsigned long long)bits << 20) |
                                (unsigned long long)(0xFFFFFu - j));
      }
    }
  }
  barrier_sync(barc, flags, 0, bid, NBLK, true);

  // ---- Phase C: rank-based top-1000 + box decode (blocks 0..15) ----
  if (bid < 16) {
    int c = bid * 256 + tid;
    unsigned M = ldg32(cand_cnt);
    if (M > 4096u) M = 4096u;
    unsigned long long mykey = (c < (int)M) ? ldg64(&cand[c]) : 0ull;
    unsigned rank = 0;
    int ntile = (int)((M + 255u) >> 8);
    for (int tile = 0; tile < ntile; tile++) {
      __syncthreads();
      int src = tile * 256 + tid;
      s_key[tid] = (src < (int)M) ? ldg64(&cand[src]) : 0ull;
      __syncthreads();
#pragma unroll 8
      for (int q = 0; q < 256; q++) rank += (s_key[q] > mykey) ? 1u : 0u;
    }
    if (c < (int)M && rank < TOPK) {
      int r = (int)rank;
      unsigned j = 0xFFFFFu - (unsigned)(mykey & 0xFFFFFull);
      unsigned hw = j / 9u;
      unsigned a = j - hw * 9u;
      int lab = labels_all[a * 65536u + hw];
      unsigned base = a * 4u * 65536u + hw;
      double r0 = (double)reg_pred[base];
      double r1 = (double)reg_pred[base + 65536u];
      double r2 = (double)reg_pred[base + 131072u];
      double r3 = (double)reg_pred[base + 196608u];
      double ax = (double)anchors[j * 4u + 0], ay = (double)anchors[j * 4u + 1];
      double aw = (double)anchors[j * 4u + 2], ah = (double)anchors[j * 4u + 3];
      double ox = fmin(fmax(r0 * aw, -CTR_CLAMP), CTR_CLAMP);
      double oy = fmin(fmax(r1 * ah, -CTR_CLAMP), CTR_CLAMP);
      double cx = ax + ox, cy = ay + oy;
      double ww = aw * exp(fmin(r2, SCALE_CLAMP));
      double hh = ah * exp(fmin(r3, SCALE_CLAMP));
      float x1 = (float)fmin(fmax((cx - 0.5 * ww) * (1.0 / IMGF), 0.0), 1.0);
      float y1 = (float)fmin(fmax((cy - 0.5 * hh) * (1.0 / IMGF), 0.0), 1.0);
      float x2 = (float)fmin(fmax((cx + 0.5 * ww) * (1.0 / IMGF), 0.0), 1.0);
      float y2 = (float)fmin(fmax((cy + 0.5 * hh) * (1.0 / IMGF), 0.0), 1.0);
      // final outputs read only by host: plain stores are fine
      out[1000 + r] = (float)lab;
      out[2000 + 4 * r + 0] = x1;
      out[2000 + 4 * r + 1] = y1;
      out[2000 + 4 * r + 2] = x2;
      out[2000 + 4 * r + 3] = y2;
      // values read by later phases: agent-scope publish
      stg32((unsigned*)&out[r], (unsigned)(mykey >> 20));
      stg32((unsigned*)&boxes_s[4 * r + 0], __float_as_uint(x1));
      stg32((unsigned*)&boxes_s[4 * r + 1], __float_as_uint(y1));
      stg32((unsigned*)&boxes_s[4 * r + 2], __float_as_uint(x2));
      stg32((unsigned*)&boxes_s[4 * r + 3], __float_as_uint(y2));
      stg32((unsigned*)&labels_s[r], (unsigned)lab);
    }
  }
  barrier_sync(barc, flags, 1, bid, 16, bid < 16);

  // ---- Phase D: suppression bit-matrix (rows bid and bid+500) ----
  for (int t = tid; t < 4000; t += 256)
    s_bx[t] = __uint_as_float(ldg32((const unsigned*)&boxes_s[t]));
  for (int t = tid; t < 1000; t += 256)
    s_lb[t] = (int)ldg32((const unsigned*)&labels_s[t]);
  __syncthreads();
  for (int half = 0; half < 2; half++) {
    int i = bid + half * NBLK;
    double ix1 = (double)s_bx[4 * i], iy1 = (double)s_bx[4 * i + 1];
    double ix2 = (double)s_bx[4 * i + 2], iy2 = (double)s_bx[4 * i + 3];
    double ia = (ix2 - ix1) * (iy2 - iy1);
    int il = s_lb[i];
    for (int rep = 0; rep < 4; rep++) {
      int j = rep * 256 + tid;
      bool s = false;
      if (j < TOPK && j > i && s_lb[j] == il) {
        double jx1 = (double)s_bx[4 * j], jy1 = (double)s_bx[4 * j + 1];
        double jx2 = (double)s_bx[4 * j + 2], jy2 = (double)s_bx[4 * j + 3];
        double xx1 = fmax(ix1, jx1), yy1 = fmax(iy1, jy1);
        double xx2 = fmin(ix2, jx2), yy2 = fmin(iy2, jy2);
        double inter = fmax(1e-28, xx2 - xx1) * fmax(1e-28, yy2 - yy1);
        double ja = (jx2 - jx1) * (jy2 - jy1);
        double iou = inter / (ia + ja - inter + 1e-14);
        s = iou > NMS_T;
      }
      unsigned long long w = __ballot(s);
      if ((tid & 63) == 0)
        stg64(&supB[(rep * 4 + (tid >> 6)) * 1024 + i], w);
    }
  }
  // barrier 2: everyone arrives; only block 0 waits (others exit, freeing CUs)
  __syncthreads();   // drain vmcnt: publishes supB
  if (tid == 0)
    __hip_atomic_fetch_add(lslot(barc, 2 * 8 + (bid & 7)), 1u, __ATOMIC_RELAXED,
                           __HIP_MEMORY_SCOPE_AGENT);
  if (bid != 0) return;
  if (tid == 0) {
    for (int it = 0; it < SPIN_CAP; it++) {
      unsigned s = 0;
#pragma unroll
      for (int i = 0; i < 8; i++)
        s += __hip_atomic_load(lslot(barc, 2 * 8 + i), __ATOMIC_RELAXED,
                               __HIP_MEMORY_SCOPE_AGENT);
      if (s >= NBLK) break;
      __builtin_amdgcn_s_sleep(2);
    }
  }
  __syncthreads();
  asm volatile("" ::: "memory");

  // ---- Phase E: greedy NMS (block 0, wave 0) ----
  if (tid < 64) {
    int lane = tid;
    float* keep_out = out + 6000;
    unsigned long long inval[16];
#pragma unroll
    for (int m = 0; m < 16; m++) {
      int j = m * 64 + lane;
      bool bad = (j >= TOPK) ||
                 (__uint_as_float(ldg32((const unsigned*)&out[j])) < CONF);
      inval[m] = __ballot(bad);
    }
    unsigned long long kept[16];
#pragma unroll
    for (int b = 0; b < 16; b++) {
      unsigned long long acc = 0ull;
#pragma unroll
      for (int m = 0; m < b; m++) {
        unsigned long long r = ldg64(&supB[b * 1024 + m * 64 + lane]);
        if ((kept[m] >> lane) & 1ull) acc |= r;
      }
      if (b > 0) {
#pragma unroll
        for (int s = 1; s < 64; s <<= 1) acc |= shflxor64(acc, s);
      }
      unsigned alo = __builtin_amdgcn_readfirstlane((unsigned)acc);
      unsigned ahi = __builtin_amdgcn_readfirstlane((unsigned)(acc >> 32));
      unsigned long long cur = inval[b] | (((unsigned long long)ahi << 32) | alo);
      unsigned long long diag = ldg64(&supB[b * 1024 + b * 64 + lane]);
      unsigned dlo = (unsigned)diag, dhi = (unsigned)(diag >> 32);
#pragma unroll 8
      for (int k = 0; k < 64; k++) {
        unsigned rlo = __builtin_amdgcn_readlane(dlo, k);
        unsigned rhi = __builtin_amdgcn_readlane(dhi, k);
        unsigned long long rk = ((unsigned long long)rhi << 32) | rlo;
        unsigned long long take = ((cur >> k) & 1ull) ? 0ull : rk;
        cur |= take;
      }
      kept[b] = ~cur;
    }
#pragma unroll
    for (int m = 0; m < 16; m++) {
      int j = m * 64 + lane;
      if (j < TOPK) keep_out[j] = ((kept[m] >> lane) & 1ull) ? 1.0f : 0.0f;
    }
  }
}

extern "C" void kernel_launch(void* const* d_in, const int* in_sizes, int n_in,
                              void* d_out, int out_size, void* d_ws, size_t ws_size,
                              hipStream_t stream) {
  const float* obj = (const float*)d_in[0];
  const float* cls = (const float*)d_in[1];
  const float* reg = (const float*)d_in[2];
  const float* anc = (const float*)d_in[3];
  float* out = (float*)d_out;
  char* ws = (char*)d_ws;

  unsigned* bits_all = (unsigned*)(ws + BITS_OFF);
  int* labels_all = (int*)(ws + LABELS_OFF);
  unsigned* hist = (unsigned*)(ws + HIST_OFF);
  unsigned* cand_cnt = (unsigned*)(ws + CNT_OFF);
  unsigned* barc = (unsigned*)(ws + BARC_OFF);
  unsigned* flags = (unsigned*)(ws + FLAG_OFF);
  unsigned long long* cand = (unsigned long long*)(ws + CAND_OFF);
  float* boxes_s = (float*)(ws + BOXES_OFF);
  int* labels_s = (int*)(ws + LABS_OFF);
  unsigned long long* supB = (unsigned long long*)(ws + SUPB_OFF);

  // zeroes hist + cand_cnt + barrier counters + flags in one shot
  hipMemsetAsync(ws + HIST_OFF, 0, ZERO_LEN, stream);

  k_score<<<576, 256, 0, stream>>>((const float4*)obj, (const float4*)cls, bits_all,
                                   labels_all, hist);

  void* kargs[] = {(void*)&hist,     (void*)&bits_all, (void*)&labels_all,
                   (void*)&reg,      (void*)&anc,      (void*)&cand_cnt,
                   (void*)&barc,     (void*)&flags,    (void*)&cand,
                   (void*)&out,      (void*)&boxes_s,  (void*)&labels_s,
                   (void*)&supB};
  hipLaunchCooperativeKernel((const void*)k_tail2, dim3(NBLK), dim3(256), kargs, 0,
                             stream);
}

// Round 5
// 393.221 us; speedup vs baseline: 1.5354x; 1.0258x over previous
//
#include <hip/hip_runtime.h>
#include <stdint.h>

#define NA 9
#define NC 80
#define NTOT 589824        // 256*256*9
#define NT4  147456        // NTOT/4
#define TOPK 1000
#define CONF 0.05f
#define NMS_T 0.6
#define CTR_CLAMP 32.0
#define IMGF 2048.0
#define SCALE_CLAMP 4.135166556742356   // log(1000/16)

// ---- workspace byte offsets ----
// All sync words padded to 256B lines (round-2 lesson: agent-scope ops
// serialize per LLC line; shared line = ~30us/barrier).
#define BITS_OFF   0u          // NTOT u32 f32-score bits, planar [a][hw]
#define LABELS_OFF 2359296u    // NTOT i32, planar
#define HIST_OFF   4718592u    // 16384 u32 (64KB)
#define CNT_OFF    4784128u    // cand counter, own 256B line
#define BARC_OFF   4784384u    // 4 barriers x 8 counters, 256B stride (8192B)
#define FLAG_OFF   4792576u    // 4 barriers x 8 flag copies, 256B stride (8192B)
#define INITF_OFF  4800768u    // 8 init-done u64 magic flags, 256B stride (2048B)
#define CAND_OFF   4802816u    // 4096 u64 (32KB)
#define BOXES_OFF  4835584u    // 4000 f32
#define LABS_OFF   4851584u    // 1000 i32
#define SUPB_OFF   4855584u    // 16*1024 u64 transposed (128KB)

#define NBLK 512               // 64KB LDS -> exactly 2 blocks/CU -> 512 co-resident
#define SPIN_CAP 200000        // ~12ms fail-fast: deadlock -> wrong answer, not hang
// distinct 32-bit halves: a repeated-32-bit poison fill can never equal this
#define INIT_MAGIC 0x9E3779B97F4A7C15ull

// ---- agent-scope (cross-XCD coherent, L2-bypassing) accessors ----
__device__ __forceinline__ void stg32(unsigned* p, unsigned v) {
  __hip_atomic_store(p, v, __ATOMIC_RELAXED, __HIP_MEMORY_SCOPE_AGENT);
}
__device__ __forceinline__ unsigned ldg32(const unsigned* p) {
  return __hip_atomic_load((unsigned*)p, __ATOMIC_RELAXED, __HIP_MEMORY_SCOPE_AGENT);
}
__device__ __forceinline__ void stg64(unsigned long long* p, unsigned long long v) {
  __hip_atomic_store(p, v, __ATOMIC_RELAXED, __HIP_MEMORY_SCOPE_AGENT);
}
__device__ __forceinline__ unsigned long long ldg64(const unsigned long long* p) {
  return __hip_atomic_load((unsigned long long*)p, __ATOMIC_RELAXED,
                           __HIP_MEMORY_SCOPE_AGENT);
}

__device__ __forceinline__ unsigned* lslot(unsigned* base, int idx) {
  return (unsigned*)((char*)base + (size_t)idx * 256u);
}

// Lightweight device barrier, no cache maintenance (verified round 4).
// publish (stg*) -> __syncthreads (vmcnt(0) drain = completion at LLC) ->
// tid0 arrival RMW -> block0 polls 8 counter lines, fans out 8 flag copies ->
// other blocks poll only their own flag copy.
__device__ __forceinline__ void barrier_sync(unsigned* cnts, unsigned* flags,
                                             int b, int bid, unsigned target,
                                             bool i_arrive) {
  __syncthreads();
  if (threadIdx.x == 0) {
    if (i_arrive)
      __hip_atomic_fetch_add(lslot(cnts, b * 8 + (bid & 7)), 1u, __ATOMIC_RELAXED,
                             __HIP_MEMORY_SCOPE_AGENT);
    if (bid == 0) {
      for (int it = 0; it < SPIN_CAP; it++) {
        unsigned s = 0;
#pragma unroll
        for (int i = 0; i < 8; i++)
          s += __hip_atomic_load(lslot(cnts, b * 8 + i), __ATOMIC_RELAXED,
                                 __HIP_MEMORY_SCOPE_AGENT);
        if (s >= target) break;
        __builtin_amdgcn_s_sleep(2);
      }
#pragma unroll
      for (int i = 0; i < 8; i++)
        __hip_atomic_store(lslot(flags, b * 8 + i), 1u, __ATOMIC_RELAXED,
                           __HIP_MEMORY_SCOPE_AGENT);
    } else {
      for (int it = 0; it < SPIN_CAP; it++) {
        if (__hip_atomic_load(lslot(flags, b * 8 + (bid & 7)), __ATOMIC_RELAXED,
                              __HIP_MEMORY_SCOPE_AGENT) != 0u)
          break;
        __builtin_amdgcn_s_sleep(2);
      }
    }
  }
  __syncthreads();
  asm volatile("" ::: "memory");
}

// ---- cephes f32 exp/log (matches the CPU reference's rounding; DO NOT TOUCH) ----
__device__ __forceinline__ float cexpf(float x) {
#pragma clang fp contract(off)
  float m = floorf(__builtin_fmaf(x, 1.44269504088896341f, 0.5f));
  float r = __builtin_fmaf(m, -0.693359375f, x);
  r = __builtin_fmaf(m, 2.12194440e-4f, r);
  float r2 = r * r;
  float y = 1.9875691500E-4f;
  y = __builtin_fmaf(y, r, 1.3981999507E-3f);
  y = __builtin_fmaf(y, r, 8.3334519073E-3f);
  y = __builtin_fmaf(y, r, 4.1665795894E-2f);
  y = __builtin_fmaf(y, r, 1.6666665459E-1f);
  y = __builtin_fmaf(y, r, 5.0000001201E-1f);
  y = __builtin_fmaf(y, r2, r) + 1.0f;
  return ldexpf(y, (int)m);
}

__device__ __forceinline__ float clogf_(float xin) {
#pragma clang fp contract(off)
  unsigned b = __float_as_uint(xin);
  int e = (int)(b >> 23) - 126;
  float m = __uint_as_float((b & 0x007FFFFFu) | 0x3F000000u);
  if (m < 0.707106781186547524f) { e -= 1; m = m + m; }
  float x = m - 1.0f;
  float z = x * x;
  float y = 7.0376836292E-2f;
  y = __builtin_fmaf(y, x, -1.1514610310E-1f);
  y = __builtin_fmaf(y, x, 1.1676998740E-1f);
  y = __builtin_fmaf(y, x, -1.2420140846E-1f);
  y = __builtin_fmaf(y, x, 1.4249322787E-1f);
  y = __builtin_fmaf(y, x, -1.6668057665E-1f);
  y = __builtin_fmaf(y, x, 2.0000714765E-1f);
  y = __builtin_fmaf(y, x, -2.4999993993E-1f);
  y = __builtin_fmaf(y, x, 3.3333331174E-1f);
  y = y * x * z;
  float ef = (float)e;
  y = __builtin_fmaf(ef, -2.12194440e-4f, y);
  y = __builtin_fmaf(-0.5f, z, y);
  float res = x + y;
  res = __builtin_fmaf(ef, 0.693359375f, res);
  return res;
}

__device__ __forceinline__ unsigned long long shflxor64(unsigned long long v, int m) {
  unsigned lo = __shfl_xor((unsigned)v, m, 64);
  unsigned hi = __shfl_xor((unsigned)(v >> 32), m, 64);
  return ((unsigned long long)hi << 32) | lo;
}

// Single fused kernel: init(block0) + score/hist -> B0 -> cutoff(redundant) +
// compact -> B1 -> rank/decode -> B2 -> sup matrix -> B3 -> nms(block0).
// The 64KB LDS histogram is overlaid with all tail-phase LDS (barrier-separated).
// Cross-phase global data is published with agent-scope stores; plain loads on
// the consumer side are safe because no XCD L2 ever holds those lines (writers
// bypass L2, and each region is read for the first time after its barrier).
__global__ __launch_bounds__(256) void k_fused(
    const float4* __restrict__ obj4, const float4* __restrict__ cls4,
    unsigned* __restrict__ bits_all, int* __restrict__ labels_all,
    unsigned* __restrict__ hist, const float* __restrict__ reg_pred,
    const float* __restrict__ anchors, unsigned* __restrict__ cand_cnt,
    unsigned* __restrict__ barc, unsigned* __restrict__ flags,
    unsigned* __restrict__ initf, unsigned long long* __restrict__ cand,
    float* __restrict__ out, float* __restrict__ boxes_s,
    int* __restrict__ labels_s, unsigned long long* __restrict__ supB) {
  int tid = threadIdx.x;
  int bid = blockIdx.x;

  __shared__ __align__(16) unsigned lh[16384];   // 64KB, overlaid per phase

  // ---- Phase 0: LDS hist zero (all blocks) + global sync-word init (block 0).
  for (int i = tid; i < 16384; i += 256) lh[i] = 0u;
  if (bid == 0) {
    for (int i = tid; i < 16384; i += 256) stg32(&hist[i], 0u);
    if (tid == 0) stg32(cand_cnt, 0u);
    if (tid < 32) {
      stg32(lslot(barc, tid), 0u);
      stg32(lslot(flags, tid), 0u);
    }
  }
  __syncthreads();   // lh zero visible; block0's global zeros drained (vmcnt)
  if (bid == 0 && tid < 8)
    stg64((unsigned long long*)lslot(initf, tid), INIT_MAGIC);

  // ---- Phase 1: score + argmax + LDS histogram (grid-stride over NT4) ----
  {
#pragma clang fp contract(off)
    for (unsigned t4 = (unsigned)bid * 256u + (unsigned)tid; t4 < (unsigned)NT4;
         t4 += (unsigned)(NBLK * 256)) {
      int a = (int)(t4 >> 14);
      int rem = (int)(t4 & 16383u);
      float4 ov = obj4[t4];
      float ob[4] = {ov.x, ov.y, ov.z, ov.w};
      float best[4] = {-1e30f, -1e30f, -1e30f, -1e30f};
      int bc[4] = {0, 0, 0, 0};
      const float4* cp = cls4 + a * 80 * 16384 + rem;
#pragma unroll 8
      for (int c = 0; c < 80; c++) {
        float4 cv = cp[c * 16384];
        float cl[4] = {cv.x, cv.y, cv.z, cv.w};
#pragma unroll
        for (int k = 0; k < 4; k++) {
          if (cl[k] > best[k]) { best[k] = cl[k]; bc[k] = c; }  // strict >
        }
      }
      unsigned bv[4];
#pragma unroll
      for (int k = 0; k < 4; k++) {
        float c = best[k], o = ob[k];
        float ec = cexpf(c);
        float eo = cexpf(o);
        float L = clogf_((1.0f + ec) + eo);
        float nrm = (c + o) - L;
        float p = 1.0f / (1.0f + cexpf(-nrm));
        bv[k] = __float_as_uint(p);            // p in (0,1): order == bit order
        atomicAdd(&lh[bv[k] >> 16], 1u);
      }
      unsigned po = (unsigned)(a * 65536 + rem * 4);   // planar, 16B-aligned
      // publish via agent-scope stores (cross-barrier consumers on other XCDs)
      stg64((unsigned long long*)&bits_all[po],
            (unsigned long long)bv[0] | ((unsigned long long)bv[1] << 32));
      stg64((unsigned long long*)&bits_all[po + 2],
            (unsigned long long)bv[2] | ((unsigned long long)bv[3] << 32));
      stg64((unsigned long long*)&labels_all[po],
            (unsigned long long)(unsigned)bc[0] |
                ((unsigned long long)(unsigned)bc[1] << 32));
      stg64((unsigned long long*)&labels_all[po + 2],
            (unsigned long long)(unsigned)bc[2] |
                ((unsigned long long)(unsigned)bc[3] << 32));
    }
  }
  __syncthreads();   // all lh atomics done
  // wait init-done before merging into global hist (block0 finished ~30us ago)
  if (tid == 0) {
    for (int it = 0; it < SPIN_CAP; it++) {
      if (ldg64((unsigned long long*)lslot(initf, bid & 7)) == INIT_MAGIC) break;
      __builtin_amdgcn_s_sleep(2);
    }
  }
  __syncthreads();
  for (int b = tid; b < 16384; b += 256) {
    unsigned v = lh[b];
    if (v) atomicAdd(&hist[b], v);
  }
  barrier_sync(barc, flags, 0, bid, NBLK, true);

  // ---- Phase 2: cutoff bin, redundantly per block (plain loads: hist lines
  // were only ever written via LLC-bypassing ops -> first-touch L2 fill is fresh)
  unsigned cB;
  {
    unsigned base = (unsigned)tid * 64u;
    unsigned s = 0;
#pragma unroll 8
    for (int b = 0; b < 64; b++) s += hist[base + b];
    unsigned v = s;
    lh[tid] = v;
    __syncthreads();
    for (int off = 1; off < 256; off <<= 1) {
      unsigned add = (tid + off < 256) ? lh[tid + off] : 0u;
      __syncthreads();
      v += add;
      lh[tid] = v;
      __syncthreads();
    }
    unsigned nxt = (tid < 255) ? lh[tid + 1] : 0u;
    if (v >= TOPK && nxt < TOPK) { lh[260] = (unsigned)tid; lh[261] = nxt; }
    __syncthreads();
    unsigned C = lh[260];
    unsigned above = lh[261];
    if (tid < 64) {
      unsigned h = hist[C * 64u + (unsigned)tid];
      unsigned acc = h;
      for (int off = 1; off < 64; off <<= 1) {
        unsigned o = __shfl_down(acc, off, 64);
        if (tid + off < 64) acc += o;
      }
      acc += above;
      if (acc >= TOPK && (tid == 63 || (acc - h) < TOPK))
        lh[262] = C * 64u + (unsigned)tid;
    }
    __syncthreads();
    cB = lh[262];
  }

  // ---- Phase 3: compact entries with bin >= cutB into u64 keys (publish) ----
  for (unsigned t = (unsigned)bid * 256u + (unsigned)tid; t < (unsigned)NTOT;
       t += (unsigned)(NBLK * 256)) {
    unsigned bits = bits_all[t];
    bool win = (bits >> 16) >= cB;
    unsigned long long m = __ballot(win);
    if (m != 0ull) {
      int lane = tid & 63;
      int leader = __ffsll((long long)m) - 1;
      unsigned base2 = 0;
      if (lane == leader) base2 = atomicAdd(cand_cnt, (unsigned)__popcll(m));
      base2 = __shfl(base2, leader, 64);
      if (win) {
        unsigned a = t >> 16;
        unsigned hw = t & 65535u;
        unsigned j = hw * 9u + a;
        unsigned pos = base2 + (unsigned)__popcll(m & ((1ull << lane) - 1ull));
        if (pos < 4096u)
          stg64(&cand[pos], ((unsigned long long)bits << 20) |
                                (unsigned long long)(0xFFFFFu - j));
      }
    }
  }
  barrier_sync(barc, flags, 1, bid, NBLK, true);

  // ---- Phase 4: rank-based top-1000 + box decode (blocks 0..15) ----
  if (bid < 16) {
    unsigned long long* s_key = (unsigned long long*)lh;
    int c = bid * 256 + tid;
    unsigned M = ldg32(cand_cnt);
    if (M > 4096u) M = 4096u;
    unsigned long long mykey = (c < (int)M) ? ldg64(&cand[c]) : 0ull;
    unsigned rank = 0;
    int ntile = (int)((M + 255u) >> 8);
    for (int tile = 0; tile < ntile; tile++) {
      __syncthreads();
      int src = tile * 256 + tid;
      s_key[tid] = (src < (int)M) ? ldg64(&cand[src]) : 0ull;
      __syncthreads();
#pragma unroll 8
      for (int q = 0; q < 256; q++) rank += (s_key[q] > mykey) ? 1u : 0u;
    }
    if (c < (int)M && rank < TOPK) {
      int r = (int)rank;
      unsigned j = 0xFFFFFu - (unsigned)(mykey & 0xFFFFFull);
      unsigned hw = j / 9u;
      unsigned a = j - hw * 9u;
      int lab = labels_all[a * 65536u + hw];
      unsigned base = a * 4u * 65536u + hw;
      double r0 = (double)reg_pred[base];
      double r1 = (double)reg_pred[base + 65536u];
      double r2 = (double)reg_pred[base + 131072u];
      double r3 = (double)reg_pred[base + 196608u];
      double ax = (double)anchors[j * 4u + 0], ay = (double)anchors[j * 4u + 1];
      double aw = (double)anchors[j * 4u + 2], ah = (double)anchors[j * 4u + 3];
      double ox = fmin(fmax(r0 * aw, -CTR_CLAMP), CTR_CLAMP);
      double oy = fmin(fmax(r1 * ah, -CTR_CLAMP), CTR_CLAMP);
      double cx = ax + ox, cy = ay + oy;
      double ww = aw * exp(fmin(r2, SCALE_CLAMP));
      double hh = ah * exp(fmin(r3, SCALE_CLAMP));
      float x1 = (float)fmin(fmax((cx - 0.5 * ww) * (1.0 / IMGF), 0.0), 1.0);
      float y1 = (float)fmin(fmax((cy - 0.5 * hh) * (1.0 / IMGF), 0.0), 1.0);
      float x2 = (float)fmin(fmax((cx + 0.5 * ww) * (1.0 / IMGF), 0.0), 1.0);
      float y2 = (float)fmin(fmax((cy + 0.5 * hh) * (1.0 / IMGF), 0.0), 1.0);
      // final outputs read only by host: plain stores are fine
      out[1000 + r] = (float)lab;
      out[2000 + 4 * r + 0] = x1;
      out[2000 + 4 * r + 1] = y1;
      out[2000 + 4 * r + 2] = x2;
      out[2000 + 4 * r + 3] = y2;
      // values read by later phases: agent-scope publish
      stg32((unsigned*)&out[r], (unsigned)(mykey >> 20));
      stg32((unsigned*)&boxes_s[4 * r + 0], __float_as_uint(x1));
      stg32((unsigned*)&boxes_s[4 * r + 1], __float_as_uint(y1));
      stg32((unsigned*)&boxes_s[4 * r + 2], __float_as_uint(x2));
      stg32((unsigned*)&boxes_s[4 * r + 3], __float_as_uint(y2));
      stg32((unsigned*)&labels_s[r], (unsigned)lab);
    }
  }
  barrier_sync(barc, flags, 2, bid, 16, bid < 16);

  // ---- Phase 5: suppression bit-matrix (rows bid and bid+512) ----
  {
    float* s_bx = (float*)lh;
    int* s_lb = (int*)((char*)lh + 16000);
    for (int t = tid; t < 4000; t += 256)
      s_bx[t] = __uint_as_float(ldg32((const unsigned*)&boxes_s[t]));
    for (int t = tid; t < 1000; t += 256)
      s_lb[t] = (int)ldg32((const unsigned*)&labels_s[t]);
    __syncthreads();
    for (int half = 0; half < 2; half++) {
      int i = bid + half * NBLK;
      if (i < TOPK) {
        double ix1 = (double)s_bx[4 * i], iy1 = (double)s_bx[4 * i + 1];
        double ix2 = (double)s_bx[4 * i + 2], iy2 = (double)s_bx[4 * i + 3];
        double ia = (ix2 - ix1) * (iy2 - iy1);
        int il = s_lb[i];
        for (int rep = 0; rep < 4; rep++) {
          int j = rep * 256 + tid;
          bool s = false;
          if (j < TOPK && j > i && s_lb[j] == il) {
            double jx1 = (double)s_bx[4 * j], jy1 = (double)s_bx[4 * j + 1];
            double jx2 = (double)s_bx[4 * j + 2], jy2 = (double)s_bx[4 * j + 3];
            double xx1 = fmax(ix1, jx1), yy1 = fmax(iy1, jy1);
            double xx2 = fmin(ix2, jx2), yy2 = fmin(iy2, jy2);
            double inter = fmax(1e-28, xx2 - xx1) * fmax(1e-28, yy2 - yy1);
            double ja = (jx2 - jx1) * (jy2 - jy1);
            double iou = inter / (ia + ja - inter + 1e-14);
            s = iou > NMS_T;
          }
          unsigned long long w = __ballot(s);
          if ((tid & 63) == 0)
            stg64(&supB[(rep * 4 + (tid >> 6)) * 1024 + i], w);
        }
      }
    }
  }
  // barrier 3: everyone arrives; only block 0 waits (others exit, freeing CUs)
  __syncthreads();   // drain vmcnt: publishes supB
  if (tid == 0)
    __hip_atomic_fetch_add(lslot(barc, 3 * 8 + (bid & 7)), 1u, __ATOMIC_RELAXED,
                           __HIP_MEMORY_SCOPE_AGENT);
  if (bid != 0) return;
  if (tid == 0) {
    for (int it = 0; it < SPIN_CAP; it++) {
      unsigned s = 0;
#pragma unroll
      for (int i = 0; i < 8; i++)
        s += __hip_atomic_load(lslot(barc, 3 * 8 + i), __ATOMIC_RELAXED,
                               __HIP_MEMORY_SCOPE_AGENT);
      if (s >= NBLK) break;
      __builtin_amdgcn_s_sleep(2);
    }
  }
  __syncthreads();
  asm volatile("" ::: "memory");

  // ---- Phase 6: greedy NMS (block 0, wave 0) ----
  if (tid < 64) {
    int lane = tid;
    float* keep_out = out + 6000;
    unsigned long long inval[16];
#pragma unroll
    for (int m = 0; m < 16; m++) {
      int j = m * 64 + lane;
      bool bad = (j >= TOPK) ||
                 (__uint_as_float(ldg32((const unsigned*)&out[j])) < CONF);
      inval[m] = __ballot(bad);
    }
    unsigned long long kept[16];
#pragma unroll
    for (int b = 0; b < 16; b++) {
      unsigned long long acc = 0ull;
#pragma unroll
      for (int m = 0; m < b; m++) {
        unsigned long long r = ldg64(&supB[b * 1024 + m * 64 + lane]);
        if ((kept[m] >> lane) & 1ull) acc |= r;
      }
      if (b > 0) {
#pragma unroll
        for (int s = 1; s < 64; s <<= 1) acc |= shflxor64(acc, s);
      }
      unsigned alo = __builtin_amdgcn_readfirstlane((unsigned)acc);
      unsigned ahi = __builtin_amdgcn_readfirstlane((unsigned)(acc >> 32));
      unsigned long long cur = inval[b] | (((unsigned long long)ahi << 32) | alo);
      unsigned long long diag = ldg64(&supB[b * 1024 + b * 64 + lane]);
      unsigned dlo = (unsigned)diag, dhi = (unsigned)(diag >> 32);
#pragma unroll 8
      for (int k = 0; k < 64; k++) {
        unsigned rlo = __builtin_amdgcn_readlane(dlo, k);
        unsigned rhi = __builtin_amdgcn_readlane(dhi, k);
        unsigned long long rk = ((unsigned long long)rhi << 32) | rlo;
        unsigned long long take = ((cur >> k) & 1ull) ? 0ull : rk;
        cur |= take;
      }
      kept[b] = ~cur;
    }
#pragma unroll
    for (int m = 0; m < 16; m++) {
      int j = m * 64 + lane;
      if (j < TOPK) keep_out[j] = ((kept[m] >> lane) & 1ull) ? 1.0f : 0.0f;
    }
  }
}

extern "C" void kernel_launch(void* const* d_in, const int* in_sizes, int n_in,
                              void* d_out, int out_size, void* d_ws, size_t ws_size,
                              hipStream_t stream) {
  const float* obj = (const float*)d_in[0];
  const float* cls = (const float*)d_in[1];
  const float* reg = (const float*)d_in[2];
  const float* anc = (const float*)d_in[3];
  float* out = (float*)d_out;
  char* ws = (char*)d_ws;

  const float4* obj4 = (const float4*)obj;
  const float4* cls4 = (const float4*)cls;
  unsigned* bits_all = (unsigned*)(ws + BITS_OFF);
  int* labels_all = (int*)(ws + LABELS_OFF);
  unsigned* hist = (unsigned*)(ws + HIST_OFF);
  unsigned* cand_cnt = (unsigned*)(ws + CNT_OFF);
  unsigned* barc = (unsigned*)(ws + BARC_OFF);
  unsigned* flags = (unsigned*)(ws + FLAG_OFF);
  unsigned* initf = (unsigned*)(ws + INITF_OFF);
  unsigned long long* cand = (unsigned long long*)(ws + CAND_OFF);
  float* boxes_s = (float*)(ws + BOXES_OFF);
  int* labels_s = (int*)(ws + LABS_OFF);
  unsigned long long* supB = (unsigned long long*)(ws + SUPB_OFF);

  void* kargs[] = {(void*)&obj4,     (void*)&cls4,     (void*)&bits_all,
                   (void*)&labels_all, (void*)&hist,   (void*)&reg,
                   (void*)&anc,      (void*)&cand_cnt, (void*)&barc,
                   (void*)&flags,    (void*)&initf,    (void*)&cand,
                   (void*)&out,      (void*)&boxes_s,  (void*)&labels_s,
                   (void*)&supB};
  hipLaunchCooperativeKernel((const void*)k_fused, dim3(NBLK), dim3(256), kargs, 0,
                             stream);
}